// Round 1
// baseline (261.121 us; speedup 1.0000x reference)
//
#include <hip/hip_runtime.h>
#include <hip/hip_bf16.h>
#include <math.h>

#define MEM 2048
#define NF4 (MEM / 4)   // 512 float4 per 2048-row

__device__ __forceinline__ float wave_reduce(float v) {
#pragma unroll
    for (int off = 32; off > 0; off >>= 1)
        v += __shfl_down(v, off, 64);
    return v;
}

__device__ __forceinline__ float sigmoidf_(float x) {
    return 1.0f / (1.0f + expf(-x));
}

// Stage A: per row j compute
//   p_l[j] = ma_w[j]·lh, p_r[j] = ma_w[j]·rh  (alpha hoisted out — scalar)
//   m_l[j] = tanh(Wh_w[j]·lh + Wh_b[j] + Us_w[j]·S + Us_b[j])
//   m_r[j] = tanh(Wh_w[j]·rh + Wh_b[j] + Us_w[j]·S + Us_b[j])
//   atomically accumulate e_l += w[j]*m_l[j], e_r += w[j]*m_r[j]
// One wave per row; grid = 512 blocks x 256 threads = 2048 waves.
__global__ __launch_bounds__(256) void
k1_score(const float* __restrict__ lh, const float* __restrict__ rh,
         const float* __restrict__ S,  const float* __restrict__ w,
         const float* __restrict__ Wh_w, const float* __restrict__ Wh_b,
         const float* __restrict__ Us_w, const float* __restrict__ Us_b,
         const float* __restrict__ ma_w,
         float* __restrict__ pl, float* __restrict__ pr,
         float* __restrict__ eacc)
{
    __shared__ __align__(16) float s_lh[MEM];
    __shared__ __align__(16) float s_rh[MEM];
    __shared__ __align__(16) float s_S[MEM];
    __shared__ float s_e[8];

    const int tid = threadIdx.x;
    for (int i = tid; i < MEM; i += 256) {
        s_lh[i] = lh[i];
        s_rh[i] = rh[i];
        s_S[i]  = S[i];
    }
    __syncthreads();

    const int wave = tid >> 6;
    const int lane = tid & 63;
    const int row  = blockIdx.x * 4 + wave;

    const float4* __restrict__ wr = (const float4*)(Wh_w + (size_t)row * MEM);
    const float4* __restrict__ ur = (const float4*)(Us_w + (size_t)row * MEM);
    const float4* __restrict__ mr = (const float4*)(ma_w + (size_t)row * MEM);
    const float4* l4 = (const float4*)s_lh;
    const float4* r4 = (const float4*)s_rh;
    const float4* s4 = (const float4*)s_S;

    float awl = 0.f, awr = 0.f, aus = 0.f, aml = 0.f, amr = 0.f;
#pragma unroll 2
    for (int it = 0; it < NF4 / 64; ++it) {
        const int idx = it * 64 + lane;
        const float4 wv = wr[idx];
        const float4 uv = ur[idx];
        const float4 mv = mr[idx];
        const float4 xl = l4[idx];
        const float4 xr = r4[idx];
        const float4 xs = s4[idx];
        awl += wv.x * xl.x + wv.y * xl.y + wv.z * xl.z + wv.w * xl.w;
        awr += wv.x * xr.x + wv.y * xr.y + wv.z * xr.z + wv.w * xr.w;
        aus += uv.x * xs.x + uv.y * xs.y + uv.z * xs.z + uv.w * xs.w;
        aml += mv.x * xl.x + mv.y * xl.y + mv.z * xl.z + mv.w * xl.w;
        amr += mv.x * xr.x + mv.y * xr.y + mv.z * xr.z + mv.w * xr.w;
    }
    awl = wave_reduce(awl);
    awr = wave_reduce(awr);
    aus = wave_reduce(aus);
    aml = wave_reduce(aml);
    amr = wave_reduce(amr);

    if (lane == 0) {
        const float us = aus + Us_b[row];
        const float ml = tanhf(awl + Wh_b[row] + us);
        const float mrv = tanhf(awr + Wh_b[row] + us);
        pl[row] = aml;
        pr[row] = amr;
        const float wj = w[row];
        s_e[wave]     = wj * ml;
        s_e[4 + wave] = wj * mrv;
    }
    __syncthreads();
    if (tid == 0) {
        atomicAdd(&eacc[0], s_e[0] + s_e[1] + s_e[2] + s_e[3]);
        atomicAdd(&eacc[1], s_e[4] + s_e[5] + s_e[6] + s_e[7]);
    }
}

// Stage C: alpha from eacc; la/ra into LDS; 8 fused matvecs; gates; c, h.
// One wave per row; grid = 512 x 256.
__global__ __launch_bounds__(256) void
k2_gates(const float* __restrict__ lc, const float* __restrict__ rc,
         const float* __restrict__ pl, const float* __restrict__ pr,
         const float* __restrict__ eacc, const float* __restrict__ ma_b,
         const float* __restrict__ ilh_w,  const float* __restrict__ ilh_b,
         const float* __restrict__ irh_w,  const float* __restrict__ irh_b,
         const float* __restrict__ lflh_w, const float* __restrict__ lflh_b,
         const float* __restrict__ lfrh_w, const float* __restrict__ lfrh_b,
         const float* __restrict__ rflh_w, const float* __restrict__ rflh_b,
         const float* __restrict__ rfrh_w, const float* __restrict__ rfrh_b,
         const float* __restrict__ ulh_w,  const float* __restrict__ ulh_b,
         const float* __restrict__ urh_w,  const float* __restrict__ urh_b,
         float* __restrict__ out)
{
    __shared__ __align__(16) float s_la[MEM];
    __shared__ __align__(16) float s_ra[MEM];

    const int tid = threadIdx.x;
    const float el = eacc[0];
    const float er = eacc[1];
    const float denom = el + er;
    const float al = el / denom;
    const float ar = er / denom;

    for (int i = tid; i < MEM; i += 256) {
        const float mb = ma_b[i];
        s_la[i] = tanhf(al * pl[i] + mb);
        s_ra[i] = tanhf(ar * pr[i] + mb);
    }
    __syncthreads();

    const int wave = tid >> 6;
    const int lane = tid & 63;
    const int row  = blockIdx.x * 4 + wave;
    const size_t off = (size_t)row * MEM;

    const float4* __restrict__ il4  = (const float4*)(ilh_w  + off);
    const float4* __restrict__ ir4  = (const float4*)(irh_w  + off);
    const float4* __restrict__ lfl4 = (const float4*)(lflh_w + off);
    const float4* __restrict__ lfr4 = (const float4*)(lfrh_w + off);
    const float4* __restrict__ rfl4 = (const float4*)(rflh_w + off);
    const float4* __restrict__ rfr4 = (const float4*)(rfrh_w + off);
    const float4* __restrict__ ul4  = (const float4*)(ulh_w  + off);
    const float4* __restrict__ ur4  = (const float4*)(urh_w  + off);
    const float4* la4 = (const float4*)s_la;
    const float4* ra4 = (const float4*)s_ra;

    float ai = 0.f, bi = 0.f, alf = 0.f, blf = 0.f;
    float arf = 0.f, brf = 0.f, au = 0.f, bu = 0.f;
#pragma unroll 2
    for (int it = 0; it < NF4 / 64; ++it) {
        const int idx = it * 64 + lane;
        const float4 xa = la4[idx];
        const float4 xb = ra4[idx];
        float4 v;
        v = il4[idx];  ai  += v.x * xa.x + v.y * xa.y + v.z * xa.z + v.w * xa.w;
        v = ir4[idx];  bi  += v.x * xb.x + v.y * xb.y + v.z * xb.z + v.w * xb.w;
        v = lfl4[idx]; alf += v.x * xa.x + v.y * xa.y + v.z * xa.z + v.w * xa.w;
        v = lfr4[idx]; blf += v.x * xb.x + v.y * xb.y + v.z * xb.z + v.w * xb.w;
        v = rfl4[idx]; arf += v.x * xa.x + v.y * xa.y + v.z * xa.z + v.w * xa.w;
        v = rfr4[idx]; brf += v.x * xb.x + v.y * xb.y + v.z * xb.z + v.w * xb.w;
        v = ul4[idx];  au  += v.x * xa.x + v.y * xa.y + v.z * xa.z + v.w * xa.w;
        v = ur4[idx];  bu  += v.x * xb.x + v.y * xb.y + v.z * xb.z + v.w * xb.w;
    }

    // reduce the pairwise sums (linearity: reduce(a)+reduce(b) == reduce(a+b))
    const float gi  = wave_reduce(ai + bi);
    const float glf = wave_reduce(alf + blf);
    const float grf = wave_reduce(arf + brf);
    const float gu  = wave_reduce(au + bu);

    if (lane == 0) {
        const float ig  = sigmoidf_(gi  + ilh_b[row]  + irh_b[row]);
        const float lfg = sigmoidf_(glf + lflh_b[row] + lfrh_b[row]);
        const float rfg = sigmoidf_(grf + rflh_b[row] + rfrh_b[row]);
        const float ug  = tanhf(gu + ulh_b[row] + urh_b[row]);
        const float c = ig * ug + lfg * lc[row] + rfg * rc[row];
        out[row]       = c;
        out[MEM + row] = tanhf(c);
    }
}

extern "C" void kernel_launch(void* const* d_in, const int* in_sizes, int n_in,
                              void* d_out, int out_size, void* d_ws, size_t ws_size,
                              hipStream_t stream) {
    const float* lc = (const float*)d_in[0];
    const float* lh = (const float*)d_in[1];
    const float* rc = (const float*)d_in[2];
    const float* rh = (const float*)d_in[3];
    const float* S  = (const float*)d_in[4];
    const float* w  = (const float*)d_in[5];
    const float* Wh_w   = (const float*)d_in[6];   const float* Wh_b   = (const float*)d_in[7];
    const float* Us_w   = (const float*)d_in[8];   const float* Us_b   = (const float*)d_in[9];
    const float* ma_w   = (const float*)d_in[10];  const float* ma_b   = (const float*)d_in[11];
    const float* ilh_w  = (const float*)d_in[12];  const float* ilh_b  = (const float*)d_in[13];
    const float* irh_w  = (const float*)d_in[14];  const float* irh_b  = (const float*)d_in[15];
    const float* lflh_w = (const float*)d_in[16];  const float* lflh_b = (const float*)d_in[17];
    const float* lfrh_w = (const float*)d_in[18];  const float* lfrh_b = (const float*)d_in[19];
    const float* rflh_w = (const float*)d_in[20];  const float* rflh_b = (const float*)d_in[21];
    const float* rfrh_w = (const float*)d_in[22];  const float* rfrh_b = (const float*)d_in[23];
    const float* ulh_w  = (const float*)d_in[24];  const float* ulh_b  = (const float*)d_in[25];
    const float* urh_w  = (const float*)d_in[26];  const float* urh_b  = (const float*)d_in[27];

    float* out  = (float*)d_out;
    float* ws   = (float*)d_ws;
    float* eacc = ws;             // 2 floats (e_l, e_r)
    float* pl   = ws + 64;        // 2048 floats, 256B-aligned
    float* pr   = ws + 64 + MEM;  // 2048 floats

    hipMemsetAsync(eacc, 0, 2 * sizeof(float), stream);

    k1_score<<<MEM / 4, 256, 0, stream>>>(lh, rh, S, w, Wh_w, Wh_b, Us_w, Us_b,
                                          ma_w, pl, pr, eacc);

    k2_gates<<<MEM / 4, 256, 0, stream>>>(lc, rc, pl, pr, eacc, ma_b,
                                          ilh_w, ilh_b, irh_w, irh_b,
                                          lflh_w, lflh_b, lfrh_w, lfrh_b,
                                          rflh_w, rflh_b, rfrh_w, rfrh_b,
                                          ulh_w, ulh_b, urh_w, urh_b, out);
}

// Round 2
// 244.002 us; speedup vs baseline: 1.0702x; 1.0702x over previous
//
#include <hip/hip_runtime.h>
#include <hip/hip_bf16.h>
#include <math.h>

#define MEM 2048
#define NT  256
#define NF4 (MEM / 4)   // 512 float4 per row

__device__ __forceinline__ float dot4(float4 a, float4 b) {
    return a.x * b.x + a.y * b.y + a.z * b.z + a.w * b.w;
}

__device__ __forceinline__ float wave_reduce(float v) {
#pragma unroll
    for (int off = 32; off > 0; off >>= 1)
        v += __shfl_down(v, off, 64);
    return v;
}

__device__ __forceinline__ float sigmoidf_(float x) {
    return 1.0f / (1.0f + expf(-x));
}

// k1: one BLOCK per row (grid=2048). Per row j:
//   pl[j] = ma_w[j]·lh, pr[j] = ma_w[j]·rh        (alpha hoisted — scalar)
//   m_l = tanh(Wh_w[j]·lh + Wh_b + Us_w[j]·S + Us_b), m_r likewise
//   wml[j] = w[j]*m_l, wmr[j] = w[j]*m_r          (k2 reduces these → no atomics/memset)
// Per thread: 2 iterations × 6 independent float4 loads (named regs → MLP).
__global__ __launch_bounds__(NT) void
k1_score(const float* __restrict__ lh, const float* __restrict__ rh,
         const float* __restrict__ S,  const float* __restrict__ w,
         const float* __restrict__ Wh_w, const float* __restrict__ Wh_b,
         const float* __restrict__ Us_w, const float* __restrict__ Us_b,
         const float* __restrict__ ma_w,
         float* __restrict__ pl, float* __restrict__ pr,
         float* __restrict__ wml, float* __restrict__ wmr)
{
    __shared__ float s_red[4][5];

    const int t   = threadIdx.x;
    const int row = blockIdx.x;

    const float4* __restrict__ wh4 = (const float4*)(Wh_w + (size_t)row * MEM);
    const float4* __restrict__ us4 = (const float4*)(Us_w + (size_t)row * MEM);
    const float4* __restrict__ ma4 = (const float4*)(ma_w + (size_t)row * MEM);
    const float4* __restrict__ l4  = (const float4*)lh;
    const float4* __restrict__ r4  = (const float4*)rh;
    const float4* __restrict__ s4  = (const float4*)S;

    float awl = 0.f, awr = 0.f, aus = 0.f, aml = 0.f, amr = 0.f;
#pragma unroll
    for (int h = 0; h < 2; ++h) {
        const int i = t + h * NT;
        const float4 a  = wh4[i];
        const float4 u  = us4[i];
        const float4 m  = ma4[i];
        const float4 xl = l4[i];
        const float4 xr = r4[i];
        const float4 xs = s4[i];
        awl += dot4(a, xl);
        awr += dot4(a, xr);
        aus += dot4(u, xs);
        aml += dot4(m, xl);
        amr += dot4(m, xr);
    }
    awl = wave_reduce(awl);
    awr = wave_reduce(awr);
    aus = wave_reduce(aus);
    aml = wave_reduce(aml);
    amr = wave_reduce(amr);

    const int wv = t >> 6, ln = t & 63;
    if (ln == 0) {
        s_red[wv][0] = awl; s_red[wv][1] = awr; s_red[wv][2] = aus;
        s_red[wv][3] = aml; s_red[wv][4] = amr;
    }
    __syncthreads();
    if (t == 0) {
        float r0 = 0.f, r1 = 0.f, r2 = 0.f, r3 = 0.f, r4v = 0.f;
#pragma unroll
        for (int k = 0; k < 4; ++k) {
            r0 += s_red[k][0]; r1 += s_red[k][1]; r2 += s_red[k][2];
            r3 += s_red[k][3]; r4v += s_red[k][4];
        }
        const float us = r2 + Us_b[row];
        const float ml = tanhf(r0 + Wh_b[row] + us);
        const float mr = tanhf(r1 + Wh_b[row] + us);
        pl[row] = r3;
        pr[row] = r4v;
        const float wj = w[row];
        wml[row] = wj * ml;
        wmr[row] = wj * mr;
    }
}

// k2: one BLOCK per row (grid=2048).
//  phase 1: block-redundant reduce of wml/wmr (16 KB, L2-broadcast) → alpha
//  phase 2: la/ra = tanh(alpha*p + ma_b) into LDS
//  phase 3: 8-stream fused dot, 8 named loads per iter, block reduce, gates.
__global__ __launch_bounds__(NT) void
k2_gates(const float* __restrict__ lc, const float* __restrict__ rc,
         const float* __restrict__ pl, const float* __restrict__ pr,
         const float* __restrict__ wml, const float* __restrict__ wmr,
         const float* __restrict__ ma_b,
         const float* __restrict__ ilh_w,  const float* __restrict__ ilh_b,
         const float* __restrict__ irh_w,  const float* __restrict__ irh_b,
         const float* __restrict__ lflh_w, const float* __restrict__ lflh_b,
         const float* __restrict__ lfrh_w, const float* __restrict__ lfrh_b,
         const float* __restrict__ rflh_w, const float* __restrict__ rflh_b,
         const float* __restrict__ rfrh_w, const float* __restrict__ rfrh_b,
         const float* __restrict__ ulh_w,  const float* __restrict__ ulh_b,
         const float* __restrict__ urh_w,  const float* __restrict__ urh_b,
         float* __restrict__ out)
{
    __shared__ __align__(16) float s_la[MEM];
    __shared__ __align__(16) float s_ra[MEM];
    __shared__ float s_red[4][4];
    __shared__ float s_al[2];

    const int t   = threadIdx.x;
    const int wv  = t >> 6, ln = t & 63;
    const int row = blockIdx.x;

    // ---- phase 1: alpha (block-redundant reduction of 2x2048 floats) ----
    {
        const float4* __restrict__ wl4 = (const float4*)wml;
        const float4* __restrict__ wr4 = (const float4*)wmr;
        const float4 a0 = wl4[t], a1 = wl4[t + NT];
        const float4 b0 = wr4[t], b1 = wr4[t + NT];
        float el = a0.x + a0.y + a0.z + a0.w + a1.x + a1.y + a1.z + a1.w;
        float er = b0.x + b0.y + b0.z + b0.w + b1.x + b1.y + b1.z + b1.w;
        el = wave_reduce(el);
        er = wave_reduce(er);
        if (ln == 0) { s_red[wv][0] = el; s_red[wv][1] = er; }
    }
    __syncthreads();
    if (t == 0) {
        const float el = s_red[0][0] + s_red[1][0] + s_red[2][0] + s_red[3][0];
        const float er = s_red[0][1] + s_red[1][1] + s_red[2][1] + s_red[3][1];
        const float d  = el + er;
        s_al[0] = el / d;
        s_al[1] = er / d;
    }
    __syncthreads();
    const float al = s_al[0];
    const float ar = s_al[1];

    // ---- phase 2: la/ra into LDS ----
    {
        const float4* __restrict__ p4 = (const float4*)pl;
        const float4* __restrict__ q4 = (const float4*)pr;
        const float4* __restrict__ b4 = (const float4*)ma_b;
        float4* sla4 = (float4*)s_la;
        float4* sra4 = (float4*)s_ra;
#pragma unroll
        for (int h = 0; h < 2; ++h) {
            const int i = t + h * NT;
            const float4 p = p4[i];
            const float4 q = q4[i];
            const float4 b = b4[i];
            float4 la, ra;
            la.x = tanhf(al * p.x + b.x); ra.x = tanhf(ar * q.x + b.x);
            la.y = tanhf(al * p.y + b.y); ra.y = tanhf(ar * q.y + b.y);
            la.z = tanhf(al * p.z + b.z); ra.z = tanhf(ar * q.z + b.z);
            la.w = tanhf(al * p.w + b.w); ra.w = tanhf(ar * q.w + b.w);
            sla4[i] = la;
            sra4[i] = ra;
        }
    }
    __syncthreads();

    // ---- phase 3: 8-stream fused matvec ----
    const size_t off = (size_t)row * MEM;
    const float4* __restrict__ il4  = (const float4*)(ilh_w  + off);
    const float4* __restrict__ ir4  = (const float4*)(irh_w  + off);
    const float4* __restrict__ lfl4 = (const float4*)(lflh_w + off);
    const float4* __restrict__ lfr4 = (const float4*)(lfrh_w + off);
    const float4* __restrict__ rfl4 = (const float4*)(rflh_w + off);
    const float4* __restrict__ rfr4 = (const float4*)(rfrh_w + off);
    const float4* __restrict__ ul4  = (const float4*)(ulh_w  + off);
    const float4* __restrict__ ur4  = (const float4*)(urh_w  + off);
    const float4* sla4 = (const float4*)s_la;
    const float4* sra4 = (const float4*)s_ra;

    float gi = 0.f, glf = 0.f, grf = 0.f, gu = 0.f;
#pragma unroll
    for (int h = 0; h < 2; ++h) {
        const int i = t + h * NT;
        const float4 w0 = il4[i];
        const float4 w1 = ir4[i];
        const float4 w2 = lfl4[i];
        const float4 w3 = lfr4[i];
        const float4 w4 = rfl4[i];
        const float4 w5 = rfr4[i];
        const float4 w6 = ul4[i];
        const float4 w7 = ur4[i];
        const float4 xa = sla4[i];
        const float4 xb = sra4[i];
        gi  += dot4(w0, xa) + dot4(w1, xb);
        glf += dot4(w2, xa) + dot4(w3, xb);
        grf += dot4(w4, xa) + dot4(w5, xb);
        gu  += dot4(w6, xa) + dot4(w7, xb);
    }
    gi  = wave_reduce(gi);
    glf = wave_reduce(glf);
    grf = wave_reduce(grf);
    gu  = wave_reduce(gu);
    if (ln == 0) {
        s_red[wv][0] = gi; s_red[wv][1] = glf; s_red[wv][2] = grf; s_red[wv][3] = gu;
    }
    __syncthreads();
    if (t == 0) {
        float r0 = 0.f, r1 = 0.f, r2 = 0.f, r3 = 0.f;
#pragma unroll
        for (int k = 0; k < 4; ++k) {
            r0 += s_red[k][0]; r1 += s_red[k][1];
            r2 += s_red[k][2]; r3 += s_red[k][3];
        }
        const float ig  = sigmoidf_(r0 + ilh_b[row]  + irh_b[row]);
        const float lfg = sigmoidf_(r1 + lflh_b[row] + lfrh_b[row]);
        const float rfg = sigmoidf_(r2 + rflh_b[row] + rfrh_b[row]);
        const float ug  = tanhf(r3 + ulh_b[row] + urh_b[row]);
        const float c   = ig * ug + lfg * lc[row] + rfg * rc[row];
        out[row]       = c;
        out[MEM + row] = tanhf(c);
    }
}

extern "C" void kernel_launch(void* const* d_in, const int* in_sizes, int n_in,
                              void* d_out, int out_size, void* d_ws, size_t ws_size,
                              hipStream_t stream) {
    const float* lc = (const float*)d_in[0];
    const float* lh = (const float*)d_in[1];
    const float* rc = (const float*)d_in[2];
    const float* rh = (const float*)d_in[3];
    const float* S  = (const float*)d_in[4];
    const float* w  = (const float*)d_in[5];
    const float* Wh_w   = (const float*)d_in[6];   const float* Wh_b   = (const float*)d_in[7];
    const float* Us_w   = (const float*)d_in[8];   const float* Us_b   = (const float*)d_in[9];
    const float* ma_w   = (const float*)d_in[10];  const float* ma_b   = (const float*)d_in[11];
    const float* ilh_w  = (const float*)d_in[12];  const float* ilh_b  = (const float*)d_in[13];
    const float* irh_w  = (const float*)d_in[14];  const float* irh_b  = (const float*)d_in[15];
    const float* lflh_w = (const float*)d_in[16];  const float* lflh_b = (const float*)d_in[17];
    const float* lfrh_w = (const float*)d_in[18];  const float* lfrh_b = (const float*)d_in[19];
    const float* rflh_w = (const float*)d_in[20];  const float* rflh_b = (const float*)d_in[21];
    const float* rfrh_w = (const float*)d_in[22];  const float* rfrh_b = (const float*)d_in[23];
    const float* ulh_w  = (const float*)d_in[24];  const float* ulh_b  = (const float*)d_in[25];
    const float* urh_w  = (const float*)d_in[26];  const float* urh_b  = (const float*)d_in[27];

    float* out = (float*)d_out;
    float* ws  = (float*)d_ws;
    float* pl  = ws;               // 2048 floats, 16B-aligned
    float* pr  = ws + MEM;         // 2048
    float* wml = ws + 2 * MEM;     // 2048
    float* wmr = ws + 3 * MEM;     // 2048

    k1_score<<<MEM, NT, 0, stream>>>(lh, rh, S, w, Wh_w, Wh_b, Us_w, Us_b,
                                     ma_w, pl, pr, wml, wmr);

    k2_gates<<<MEM, NT, 0, stream>>>(lc, rc, pl, pr, wml, wmr, ma_b,
                                     ilh_w, ilh_b, irh_w, irh_b,
                                     lflh_w, lflh_b, lfrh_w, lfrh_b,
                                     rflh_w, rflh_b, rfrh_w, rfrh_b,
                                     ulh_w, ulh_b, urh_w, urh_b, out);
}